// Round 1
// baseline (604.749 us; speedup 1.0000x reference)
//
#include <hip/hip_runtime.h>
#include <hip/hip_bf16.h>

// Problem: B=32, S=2048, D=1024, C=256
//   top[b,s]   = max_c sum_d (latent[c,d]*att_diag[d]) * (tok_mult*embeds[b,s,d] + pos_table[rel_ids[b,s]+64, d])
//   top        = top*m + (m-1)*NEG        (mask affine, per (b,s))
//   p[b,s]     = softmax_s(top[b,s])
//   ctx[b,d]   = tok_diag[d] * sum_s embeds[b,s,d] * p[b,s]
//
// ws layout: top (256KB) | probs (256KB) | partial (2MB)  -> 2.62 MB total

#define HC 64
#define NEGV 1000000000000.0f

constexpr int Bb = 32, Ss = 2048, Dd = 1024, Cc = 256;
constexpr int MT = 64;    // tokens per block (pass 1)
constexpr int KT = 16;    // K chunk
constexpr int WPAD = 20;  // padded row length for W tile (floats), 16B aligned
constexpr int NSPLIT = 16;
constexpr int SCHUNK = Ss / NSPLIT; // 128

// ---------------- Pass 1: scores + max over c ----------------
__global__ __launch_bounds__(256) void k_scores_max(
    const float* __restrict__ embeds,    // [B][S][D]
    const float* __restrict__ mask,      // [B][S]
    const float* __restrict__ latent,    // [C][D]
    const float* __restrict__ att_diag,  // [D]
    const float* __restrict__ pos_table, // [132][D]
    const float* __restrict__ tok_mult,  // [1]
    const int*   __restrict__ rel_ids,   // [B][S]
    float* __restrict__ top)             // [B][S]
{
    __shared__ float sm[KT][MT];     // merged, [k][token]
    __shared__ float sw[Cc][WPAD];   // W = latent*att_diag, [c][k]

    const int t   = threadIdx.x;
    const int blk = blockIdx.x;
    const int blocks_per_b = Ss / MT;        // 32
    const int b  = blk / blocks_per_b;
    const int s0 = (blk % blocks_per_b) * MT;

    const float tm = tok_mult[0];

    // staging assignment: thread t loads 4 consecutive d for one token
    const int st_tok = t >> 2;            // 0..63
    const int st_k4  = (t & 3) * 4;       // 0,4,8,12
    const int s_tok  = s0 + st_tok;
    const int pid    = rel_ids[b * Ss + s_tok] + HC;
    const float* erow = embeds + ((size_t)b * Ss + s_tok) * Dd;
    const float* prow = pos_table + (size_t)pid * Dd;
    const float* lrow = latent + (size_t)t * Dd;  // thread t stages c = t

    const int tc = t & 31;   // c-group lane
    const int tt = t >> 5;   // token group (0..7)

    float acc[8][8];         // [token i][c j]  c = tc + 32*j (mapping irrelevant: max over c)
    #pragma unroll
    for (int i = 0; i < 8; i++)
        #pragma unroll
        for (int j = 0; j < 8; j++) acc[i][j] = 0.f;

    for (int k0 = 0; k0 < Dd; k0 += KT) {
        __syncthreads();
        // stage merged tile [KT][MT]
        {
            float4 e4 = *(const float4*)(erow + k0 + st_k4);
            float4 p4 = *(const float4*)(prow + k0 + st_k4);
            sm[st_k4 + 0][st_tok] = tm * e4.x + p4.x;
            sm[st_k4 + 1][st_tok] = tm * e4.y + p4.y;
            sm[st_k4 + 2][st_tok] = tm * e4.z + p4.z;
            sm[st_k4 + 3][st_tok] = tm * e4.w + p4.w;
        }
        // stage W tile: thread t stages row c=t, 16 floats
        #pragma unroll
        for (int q = 0; q < 4; q++) {
            float4 l4 = *(const float4*)(lrow + k0 + 4 * q);
            float4 a4 = *(const float4*)(att_diag + k0 + 4 * q);
            float4 w4 = make_float4(l4.x * a4.x, l4.y * a4.y, l4.z * a4.z, l4.w * a4.w);
            *(float4*)&sw[t][4 * q] = w4;
        }
        __syncthreads();

        #pragma unroll
        for (int kq = 0; kq < KT; kq += 4) {
            float4 wv[8];
            #pragma unroll
            for (int j = 0; j < 8; j++)
                wv[j] = *(const float4*)&sw[tc + 32 * j][kq];
            #pragma unroll
            for (int ki = 0; ki < 4; ki++) {
                float mv[8];
                float4 m0 = *(const float4*)&sm[kq + ki][tt * 8];
                float4 m1 = *(const float4*)&sm[kq + ki][tt * 8 + 4];
                mv[0] = m0.x; mv[1] = m0.y; mv[2] = m0.z; mv[3] = m0.w;
                mv[4] = m1.x; mv[5] = m1.y; mv[6] = m1.z; mv[7] = m1.w;
                #pragma unroll
                for (int j = 0; j < 8; j++) {
                    const float wk = (&wv[j].x)[ki];
                    #pragma unroll
                    for (int i = 0; i < 8; i++)
                        acc[i][j] = fmaf(mv[i], wk, acc[i][j]);
                }
            }
        }
    }

    // max over c: local 8, then across the 32-lane tc group
    #pragma unroll
    for (int i = 0; i < 8; i++) {
        float mx = acc[i][0];
        #pragma unroll
        for (int j = 1; j < 8; j++) mx = fmaxf(mx, acc[i][j]);
        #pragma unroll
        for (int o = 16; o >= 1; o >>= 1) mx = fmaxf(mx, __shfl_xor(mx, o));
        if (tc == 0) {
            const int s = s0 + tt * 8 + i;
            const float m = mask[b * Ss + s];
            top[b * Ss + s] = mx * m + (m - 1.0f) * NEGV;
        }
    }
}

// ---------------- Pass 2: softmax over s ----------------
__global__ __launch_bounds__(256) void k_softmax(
    const float* __restrict__ top, float* __restrict__ probs)
{
    const int b = blockIdx.x, t = threadIdx.x;
    const float* row = top + (size_t)b * Ss;
    float v[8];
    #pragma unroll
    for (int i = 0; i < 8; i++) v[i] = row[t + 256 * i];

    float mx = v[0];
    #pragma unroll
    for (int i = 1; i < 8; i++) mx = fmaxf(mx, v[i]);
    #pragma unroll
    for (int o = 32; o >= 1; o >>= 1) mx = fmaxf(mx, __shfl_xor(mx, o));

    __shared__ float redm[4], reds[4];
    const int w = t >> 6, ln = t & 63;
    if (ln == 0) redm[w] = mx;
    __syncthreads();
    mx = fmaxf(fmaxf(redm[0], redm[1]), fmaxf(redm[2], redm[3]));

    float sum = 0.f;
    #pragma unroll
    for (int i = 0; i < 8; i++) { v[i] = expf(v[i] - mx); sum += v[i]; }
    #pragma unroll
    for (int o = 32; o >= 1; o >>= 1) sum += __shfl_xor(sum, o);
    if (ln == 0) reds[w] = sum;
    __syncthreads();
    sum = reds[0] + reds[1] + reds[2] + reds[3];

    const float inv = 1.0f / sum;
    #pragma unroll
    for (int i = 0; i < 8; i++) probs[(size_t)b * Ss + t + 256 * i] = v[i] * inv;
}

// ---------------- Pass 3: partial context sums ----------------
__global__ __launch_bounds__(256) void k_ctx_partial(
    const float* __restrict__ embeds, const float* __restrict__ probs,
    float* __restrict__ partial)   // [B][NSPLIT][D]
{
    const int b  = blockIdx.x / NSPLIT;
    const int sp = blockIdx.x % NSPLIT;
    const int d  = threadIdx.x * 4;
    const float* base = embeds + ((size_t)b * Ss + sp * SCHUNK) * Dd;
    const float* prow = probs + (size_t)b * Ss + sp * SCHUNK;
    float4 acc = make_float4(0.f, 0.f, 0.f, 0.f);
    for (int s = 0; s < SCHUNK; s++) {
        const float p = prow[s];
        float4 e = *(const float4*)(base + (size_t)s * Dd + d);
        acc.x = fmaf(p, e.x, acc.x);
        acc.y = fmaf(p, e.y, acc.y);
        acc.z = fmaf(p, e.z, acc.z);
        acc.w = fmaf(p, e.w, acc.w);
    }
    *(float4*)(partial + ((size_t)(b * NSPLIT + sp)) * Dd + d) = acc;
}

// ---------------- Pass 4: reduce partials, apply tok_diag ----------------
__global__ __launch_bounds__(256) void k_ctx_reduce(
    const float* __restrict__ partial, const float* __restrict__ tok_diag,
    float* __restrict__ out)  // [B][D]
{
    const int b = blockIdx.x;
    const int d = threadIdx.x * 4;
    float4 acc = make_float4(0.f, 0.f, 0.f, 0.f);
    #pragma unroll
    for (int sp = 0; sp < NSPLIT; sp++) {
        float4 v = *(const float4*)(partial + ((size_t)(b * NSPLIT + sp)) * Dd + d);
        acc.x += v.x; acc.y += v.y; acc.z += v.z; acc.w += v.w;
    }
    float4 td = *(const float4*)(tok_diag + d);
    float4 o = make_float4(acc.x * td.x, acc.y * td.y, acc.z * td.z, acc.w * td.w);
    *(float4*)(out + (size_t)b * Dd + d) = o;
}

extern "C" void kernel_launch(void* const* d_in, const int* in_sizes, int n_in,
                              void* d_out, int out_size, void* d_ws, size_t ws_size,
                              hipStream_t stream) {
    const float* embeds    = (const float*)d_in[0];
    const float* mask      = (const float*)d_in[1];
    const float* latent    = (const float*)d_in[2];
    const float* att_diag  = (const float*)d_in[3];
    const float* tok_diag  = (const float*)d_in[4];
    const float* pos_table = (const float*)d_in[5];
    const float* tok_mult  = (const float*)d_in[6];
    const int*   rel_ids   = (const int*)d_in[7];
    float* out = (float*)d_out;

    char* ws = (char*)d_ws;
    float* top     = (float*)(ws);                       // 256 KB
    float* probs   = (float*)(ws + 262144);              // 256 KB
    float* partial = (float*)(ws + 524288);              // 2 MB

    k_scores_max<<<(Bb * Ss) / MT, 256, 0, stream>>>(
        embeds, mask, latent, att_diag, pos_table, tok_mult, rel_ids, top);
    k_softmax<<<Bb, 256, 0, stream>>>(top, probs);
    k_ctx_partial<<<Bb * NSPLIT, 256, 0, stream>>>(embeds, probs, partial);
    k_ctx_reduce<<<Bb, 256, 0, stream>>>(partial, tok_diag, out);
}

// Round 2
// 292.516 us; speedup vs baseline: 2.0674x; 2.0674x over previous
//
#include <hip/hip_runtime.h>
#include <hip/hip_bf16.h>

// B=32, S=2048, D=1024, C=256
//   top[b,s] = max_c sum_d (latent[c,d]*att_diag[d]) * (tm*embeds[b,s,d] + pos_table[rel+64,d])
//   p = softmax_s(top*m + (m-1)*NEG);  ctx[b,d] = tok_diag[d] * sum_s embeds*p
//
// Pass 1 strategy: split-bf16 MFMA emulation of the f32 GEMM.
//   W = latent*att_diag pre-split hi/lo bf16, stored FRAGMENT-ORDERED in ws
//   (A-operand); merged built in regs and split hi/lo (B-operand).
//   3 MFMAs per tile: hi*hi + hi*lo + lo*hi. No LDS anywhere in pass 1.
//
// ws: whi 512K | wlo 512K | top 256K | probs 256K | partial 2M = 3.5 MB

#define HC 64
#define NEGV 1000000000000.0f

constexpr int Bb = 32, Ss = 2048, Dd = 1024, Cc = 256;
constexpr int KC = 32, NKC = Dd / KC;   // k-chunk = one MFMA K, 32 chunks
constexpr int CT = Cc / 16;             // 16 c-tiles of 16 rows
constexpr int NSPLIT = 16, SCHUNK = Ss / NSPLIT;

typedef __bf16 bf16x8 __attribute__((ext_vector_type(8)));
typedef float  f32x4  __attribute__((ext_vector_type(4)));

// ---------------- Pass 0: W -> fragment-ordered bf16 hi/lo ----------------
// Fragment slot map (shared by A and B; any consistent map is valid):
//   lane = (c%16) + 16*g,  k = kc*32 + 8*g + i   (g=0..3, i=0..7)
//   dst  = ((kc*CT + c/16)*64 + lane)*8 + i
__global__ __launch_bounds__(256) void k_prep_w(
    const float* __restrict__ latent, const float* __restrict__ att_diag,
    __bf16* __restrict__ whi, __bf16* __restrict__ wlo)
{
    const int idx = blockIdx.x * 256 + threadIdx.x;   // c*Dd + k
    const int c = idx >> 10, k = idx & 1023;
    const float w = latent[idx] * att_diag[k];
    const __bf16 h = (__bf16)w;
    const __bf16 lo = (__bf16)(w - (float)h);
    const int kc = k >> 5, kr = k & 31;
    const int g = kr >> 3, i = kr & 7;
    const int lane = (c & 15) + 16 * g;
    const size_t dst = (((size_t)(kc * CT + (c >> 4))) * 64 + lane) * 8 + i;
    whi[dst] = h;
    wlo[dst] = lo;
}

// ---------------- Pass 1: scores via MFMA, max over c ----------------
// Block = 64 tokens, 4 waves; wave w owns tokens s0+16w..+15 x all 256 c.
// D[c][tok]: A = W (c rows), B = merged^T (tok cols).
__global__ __launch_bounds__(256) void k_scores_mfma(
    const float* __restrict__ embeds,    // [B][S][D]
    const float* __restrict__ mask,      // [B][S]
    const float* __restrict__ pos_table, // [132][D]
    const float* __restrict__ tok_mult,  // [1]
    const int*   __restrict__ rel_ids,   // [B][S]
    const __bf16* __restrict__ whi, const __bf16* __restrict__ wlo,
    float* __restrict__ top)             // [B][S]
{
    const int t  = threadIdx.x;
    const int wv = t >> 6;      // wave 0..3
    const int l  = t & 63;      // lane
    const int lr = l & 15;      // row/col within 16x16
    const int lg = l >> 4;      // k-group 0..3

    const int blk = blockIdx.x;
    const int b   = blk >> 5;          // S/64 = 32 token-blocks per batch
    const int s0  = (blk & 31) * 64;
    const int tok = s0 + wv * 16 + lr; // this lane's token

    const float tm  = tok_mult[0];
    const int   pid = rel_ids[b * Ss + tok] + HC;
    const float* erow = embeds    + ((size_t)b * Ss + tok) * Dd;
    const float* prow = pos_table + (size_t)pid * Dd;

    f32x4 acc[CT];
    #pragma unroll
    for (int ct = 0; ct < CT; ct++) acc[ct] = (f32x4){0.f, 0.f, 0.f, 0.f};

    const bf16x8* whi8 = (const bf16x8*)whi;
    const bf16x8* wlo8 = (const bf16x8*)wlo;

    for (int kc = 0; kc < NKC; kc++) {
        const int k0 = kc * KC + lg * 8;
        // build B fragment: merged[tok][k0..k0+7], split hi/lo in regs
        float e[8], p[8];
        *(f32x4*)&e[0] = *(const f32x4*)(erow + k0);
        *(f32x4*)&e[4] = *(const f32x4*)(erow + k0 + 4);
        *(f32x4*)&p[0] = *(const f32x4*)(prow + k0);
        *(f32x4*)&p[4] = *(const f32x4*)(prow + k0 + 4);
        bf16x8 bh, bl;
        #pragma unroll
        for (int i = 0; i < 8; i++) {
            const float x = fmaf(tm, e[i], p[i]);
            const __bf16 h = (__bf16)x;
            bh[i] = h;
            bl[i] = (__bf16)(x - (float)h);
        }
        const int fbase = kc * CT * 64 + l;
        #pragma unroll
        for (int ct = 0; ct < CT; ct++) {
            const bf16x8 ah = whi8[fbase + ct * 64];
            const bf16x8 al = wlo8[fbase + ct * 64];
            acc[ct] = __builtin_amdgcn_mfma_f32_16x16x32_bf16(ah, bh, acc[ct], 0, 0, 0);
            acc[ct] = __builtin_amdgcn_mfma_f32_16x16x32_bf16(ah, bl, acc[ct], 0, 0, 0);
            acc[ct] = __builtin_amdgcn_mfma_f32_16x16x32_bf16(al, bh, acc[ct], 0, 0, 0);
        }
    }

    // max over all c for this lane's token column (col = l&15)
    float mx = acc[0][0];
    #pragma unroll
    for (int ct = 0; ct < CT; ct++)
        #pragma unroll
        for (int r = 0; r < 4; r++) mx = fmaxf(mx, acc[ct][r]);
    mx = fmaxf(mx, __shfl_xor(mx, 16));
    mx = fmaxf(mx, __shfl_xor(mx, 32));

    if (lg == 0) {
        const float mk = mask[b * Ss + tok];
        top[b * Ss + tok] = mx * mk + (mk - 1.0f) * NEGV;
    }
}

// ---------------- Pass 2: softmax over s ----------------
__global__ __launch_bounds__(256) void k_softmax(
    const float* __restrict__ top, float* __restrict__ probs)
{
    const int b = blockIdx.x, t = threadIdx.x;
    const float* row = top + (size_t)b * Ss;
    float v[8];
    #pragma unroll
    for (int i = 0; i < 8; i++) v[i] = row[t + 256 * i];

    float mx = v[0];
    #pragma unroll
    for (int i = 1; i < 8; i++) mx = fmaxf(mx, v[i]);
    #pragma unroll
    for (int o = 32; o >= 1; o >>= 1) mx = fmaxf(mx, __shfl_xor(mx, o));

    __shared__ float redm[4], reds[4];
    const int w = t >> 6, ln = t & 63;
    if (ln == 0) redm[w] = mx;
    __syncthreads();
    mx = fmaxf(fmaxf(redm[0], redm[1]), fmaxf(redm[2], redm[3]));

    float sum = 0.f;
    #pragma unroll
    for (int i = 0; i < 8; i++) { v[i] = expf(v[i] - mx); sum += v[i]; }
    #pragma unroll
    for (int o = 32; o >= 1; o >>= 1) sum += __shfl_xor(sum, o);
    if (ln == 0) reds[w] = sum;
    __syncthreads();
    sum = reds[0] + reds[1] + reds[2] + reds[3];

    const float inv = 1.0f / sum;
    #pragma unroll
    for (int i = 0; i < 8; i++) probs[(size_t)b * Ss + t + 256 * i] = v[i] * inv;
}

// ---------------- Pass 3: partial context sums ----------------
__global__ __launch_bounds__(256) void k_ctx_partial(
    const float* __restrict__ embeds, const float* __restrict__ probs,
    float* __restrict__ partial)   // [B][NSPLIT][D]
{
    const int b  = blockIdx.x / NSPLIT;
    const int sp = blockIdx.x % NSPLIT;
    const int d  = threadIdx.x * 4;
    const float* base = embeds + ((size_t)b * Ss + sp * SCHUNK) * Dd;
    const float* prow = probs + (size_t)b * Ss + sp * SCHUNK;
    float4 acc = make_float4(0.f, 0.f, 0.f, 0.f);
    for (int s = 0; s < SCHUNK; s++) {
        const float p = prow[s];
        float4 e = *(const float4*)(base + (size_t)s * Dd + d);
        acc.x = fmaf(p, e.x, acc.x);
        acc.y = fmaf(p, e.y, acc.y);
        acc.z = fmaf(p, e.z, acc.z);
        acc.w = fmaf(p, e.w, acc.w);
    }
    *(float4*)(partial + ((size_t)(b * NSPLIT + sp)) * Dd + d) = acc;
}

// ---------------- Pass 4: reduce partials, apply tok_diag ----------------
__global__ __launch_bounds__(256) void k_ctx_reduce(
    const float* __restrict__ partial, const float* __restrict__ tok_diag,
    float* __restrict__ out)  // [B][D]
{
    const int b = blockIdx.x;
    const int d = threadIdx.x * 4;
    float4 acc = make_float4(0.f, 0.f, 0.f, 0.f);
    #pragma unroll
    for (int sp = 0; sp < NSPLIT; sp++) {
        float4 v = *(const float4*)(partial + ((size_t)(b * NSPLIT + sp)) * Dd + d);
        acc.x += v.x; acc.y += v.y; acc.z += v.z; acc.w += v.w;
    }
    float4 td = *(const float4*)(tok_diag + d);
    float4 o = make_float4(acc.x * td.x, acc.y * td.y, acc.z * td.z, acc.w * td.w);
    *(float4*)(out + (size_t)b * Dd + d) = o;
}

extern "C" void kernel_launch(void* const* d_in, const int* in_sizes, int n_in,
                              void* d_out, int out_size, void* d_ws, size_t ws_size,
                              hipStream_t stream) {
    const float* embeds    = (const float*)d_in[0];
    const float* mask      = (const float*)d_in[1];
    const float* latent    = (const float*)d_in[2];
    const float* att_diag  = (const float*)d_in[3];
    const float* tok_diag  = (const float*)d_in[4];
    const float* pos_table = (const float*)d_in[5];
    const float* tok_mult  = (const float*)d_in[6];
    const int*   rel_ids   = (const int*)d_in[7];
    float* out = (float*)d_out;

    char* ws = (char*)d_ws;
    __bf16* whi    = (__bf16*)(ws);                  // 512 KB
    __bf16* wlo    = (__bf16*)(ws + 524288);         // 512 KB
    float*  top    = (float*)(ws + 1048576);         // 256 KB
    float*  probs  = (float*)(ws + 1310720);         // 256 KB
    float*  partial= (float*)(ws + 1572864);         // 2 MB

    k_prep_w<<<(Cc * Dd) / 256, 256, 0, stream>>>(latent, att_diag, whi, wlo);
    k_scores_mfma<<<(Bb * Ss) / 64, 256, 0, stream>>>(
        embeds, mask, pos_table, tok_mult, rel_ids, whi, wlo, top);
    k_softmax<<<Bb, 256, 0, stream>>>(top, probs);
    k_ctx_partial<<<Bb * NSPLIT, 256, 0, stream>>>(embeds, probs, partial);
    k_ctx_reduce<<<Bb, 256, 0, stream>>>(partial, tok_diag, out);
}